// Round 1
// baseline (5695.449 us; speedup 1.0000x reference)
//
#include <hip/hip_runtime.h>
#include <hip/hip_bf16.h>
#include <stdint.h>

#define NN 50000
#define EE 800000
#define DD 128
#define LL 4

typedef __attribute__((ext_vector_type(8))) short short8;
typedef __attribute__((ext_vector_type(4))) float f32x4;

__device__ __forceinline__ unsigned short f2bf(float x){
  unsigned u = __float_as_uint(x);
  u = (u + 0x7FFFu + ((u >> 16) & 1u)) >> 16;   // RNE
  return (unsigned short)u;
}
__device__ __forceinline__ unsigned encf(float f){   // order-preserving float->uint
  int b = __float_as_int(f);
  return (b >= 0) ? ((unsigned)b | 0x80000000u) : ~((unsigned)b);
}
__device__ __forceinline__ float decf(unsigned u){
  return (u & 0x80000000u) ? __int_as_float((int)(u & 0x7FFFFFFFu))
                           : __int_as_float((int)(~u));
}

// Stage 64 gathered fp32 rows of h into a bf16 LDS tile [64][136] (pad keeps 16B align)
__device__ __forceinline__ void stage_gather_bf16(
    unsigned short* T, const float* __restrict__ h,
    const int* __restrict__ idx, int base, int t){
  #pragma unroll
  for (int i = 0; i < 8; i++){
    int c = i*256 + t; int r = c >> 5, cc = c & 31;
    int g = idx[base + r];
    const float4 v = *(const float4*)(h + (size_t)g*DD + cc*4);
    unsigned lo = (unsigned)f2bf(v.x) | ((unsigned)f2bf(v.y) << 16);
    unsigned hi = (unsigned)f2bf(v.z) | ((unsigned)f2bf(v.w) << 16);
    *(uint2*)(T + r*136 + cc*4) = make_uint2(lo, hi);
  }
}

// acc[nt] += Atile(16x128) @ W[:, nt*16..nt*16+15]; W given transposed bf16 [n][k], row stride 136
__device__ __forceinline__ void gemm8(
    f32x4 acc[8], const short8 af[4], const unsigned short* __restrict__ wt,
    int m15, int q){
  #pragma unroll
  for (int nt = 0; nt < 8; nt++){
    #pragma unroll
    for (int ks = 0; ks < 4; ks++){
      short8 b = *(const short8*)(wt + (nt*16 + m15)*136 + ks*32 + q*8);
      acc[nt] = __builtin_amdgcn_mfma_f32_16x16x32_bf16(af[ks], b, acc[nt], 0, 0, 0);
    }
  }
}

// Cast+transpose the 16 weight matrices to bf16 WT[mat][n][k], stride 136
__global__ void prep_weights_k(const float* __restrict__ A, const float* __restrict__ B,
                               const float* __restrict__ C, const float* __restrict__ V,
                               unsigned short* __restrict__ WT){
  int mat = blockIdx.x >> 6;          // 16 mats x 64 chunks
  int chunk = blockIdx.x & 63;
  int l = mat >> 2, which = mat & 3;
  const float* W = (which == 0) ? A : (which == 1) ? B : (which == 2) ? C : V;
  W += (size_t)l*DD*DD;
  int idx = chunk*256 + threadIdx.x;  // 0..16383
  int nrow = idx >> 7, kk = idx & 127;
  WT[(size_t)mat*DD*136 + nrow*136 + kk] = f2bf(W[kk*DD + nrow]);
}

// e_hat = hs@A + hd@B + e@C ; logits = lrelu(e_hat).a (+atomicMax m) ;
// x_e = e + e_hat written back (in-place safe) ; BN(e) column sums
__global__ __launch_bounds__(256, 3) void edge_pre_k(
    const float* __restrict__ h_in, const float* __restrict__ e_in,
    const int* __restrict__ src, const int* __restrict__ dst,
    const unsigned short* __restrict__ wtA,
    const unsigned short* __restrict__ wtB,
    const unsigned short* __restrict__ wtC,
    const float* __restrict__ attn_l,
    float* __restrict__ xe_out, float* __restrict__ logits,
    unsigned* __restrict__ mmax,
    float* __restrict__ esum, float* __restrict__ esum2)
{
  __shared__ unsigned short shT[64*136];  // gathered h rows (bf16)
  __shared__ float xeT[64*132];           // e rows fp32 -> x_e
  const int t = threadIdx.x;
  const int base = blockIdx.x * 64;

  #pragma unroll
  for (int i = 0; i < 8; i++){
    int c = i*256 + t; int r = c >> 5, cc = c & 31;
    *(float4*)(xeT + r*132 + cc*4) =
        *(const float4*)(e_in + (size_t)(base + r)*DD + cc*4);
  }
  stage_gather_bf16(shT, h_in, src, base, t);
  __syncthreads();

  const int lane = t & 63, wv = t >> 6, m15 = lane & 15, q = lane >> 4;
  const int arow = wv*16 + m15;
  f32x4 acc[8];
  #pragma unroll
  for (int nt = 0; nt < 8; nt++) acc[nt] = (f32x4){0.f, 0.f, 0.f, 0.f};

  short8 af[4];
  #pragma unroll
  for (int ks = 0; ks < 4; ks++)                      // hs @ A
    af[ks] = *(const short8*)(shT + arow*136 + ks*32 + q*8);
  gemm8(acc, af, wtA, m15, q);

  #pragma unroll
  for (int ks = 0; ks < 4; ks++){                     // e @ C (cvt from fp32 LDS)
    const float* p = xeT + arow*132 + ks*32 + q*8;
    float4 v0 = *(const float4*)p, v1 = *(const float4*)(p + 4);
    short8 a;
    a[0]=(short)f2bf(v0.x); a[1]=(short)f2bf(v0.y); a[2]=(short)f2bf(v0.z); a[3]=(short)f2bf(v0.w);
    a[4]=(short)f2bf(v1.x); a[5]=(short)f2bf(v1.y); a[6]=(short)f2bf(v1.z); a[7]=(short)f2bf(v1.w);
    af[ks] = a;
  }
  gemm8(acc, af, wtC, m15, q);

  __syncthreads();                                    // all waves done with shT
  stage_gather_bf16(shT, h_in, dst, base, t);         // restage with hd rows
  __syncthreads();
  #pragma unroll
  for (int ks = 0; ks < 4; ks++)                      // hd @ B
    af[ks] = *(const short8*)(shT + arow*136 + ks*32 + q*8);
  gemm8(acc, af, wtB, m15, q);

  // logits = leaky_relu(e_hat) . attn  (rows q*4+reg, cols nt*16+m15)
  float av[8];
  #pragma unroll
  for (int nt = 0; nt < 8; nt++) av[nt] = attn_l[nt*16 + m15];
  float p4[4];
  #pragma unroll
  for (int reg = 0; reg < 4; reg++){
    float s = 0.f;
    #pragma unroll
    for (int nt = 0; nt < 8; nt++){
      float v = acc[nt][reg];
      v = (v > 0.f) ? v : 0.2f*v;
      s += v * av[nt];
    }
    p4[reg] = s;
  }
  #pragma unroll
  for (int d_ = 1; d_ < 16; d_ <<= 1){
    #pragma unroll
    for (int reg = 0; reg < 4; reg++) p4[reg] += __shfl_xor(p4[reg], d_);
  }
  if (m15 == 0){
    #pragma unroll
    for (int reg = 0; reg < 4; reg++){
      int R = base + wv*16 + q*4 + reg;
      logits[R] = p4[reg];
      atomicMax(mmax + dst[R], encf(p4[reg]));
    }
  }

  // x_e = e + e_hat (own rows only -> no cross-wave hazard)
  #pragma unroll
  for (int nt = 0; nt < 8; nt++){
    #pragma unroll
    for (int reg = 0; reg < 4; reg++){
      int rl = wv*16 + q*4 + reg;
      xeT[rl*132 + nt*16 + m15] += acc[nt][reg];
    }
  }
  __syncthreads();

  { // BN(e) column partial sums
    int col = t & 127, half = t >> 7;
    float s = 0.f, s2 = 0.f;
    #pragma unroll 4
    for (int r = half*32; r < half*32 + 32; r++){
      float v = xeT[r*132 + col]; s += v; s2 += v*v;
    }
    atomicAdd(esum + col, s);
    atomicAdd(esum2 + col, s2);
  }
  #pragma unroll
  for (int i = 0; i < 8; i++){
    int c = i*256 + t; int r = c >> 5, cc = c & 31;
    *(float4*)(xe_out + (size_t)(base + r)*DD + cc*4) =
        *(const float4*)(xeT + r*132 + cc*4);
  }
}

__global__ void edge_w_k(float* lw, const int* __restrict__ dst,
                         const unsigned* __restrict__ mmax, float* __restrict__ denom){
  int i = blockIdx.x*256 + threadIdx.x;
  float l = lw[i];
  int d = dst[i];
  float v = __expf(l - decf(mmax[d]));
  lw[i] = v;                       // logits buffer becomes w buffer
  atomicAdd(denom + d, v);
}

// msg = alpha * (hs @ V); scatter-add into agg[dst]
__global__ __launch_bounds__(256, 3) void edge_msg_k(
    const float* __restrict__ h_in, const int* __restrict__ src,
    const int* __restrict__ dst,
    const unsigned short* __restrict__ wtV,
    const float* __restrict__ wbuf, const float* __restrict__ denom,
    float* __restrict__ agg)
{
  __shared__ unsigned short shT[64*136];
  __shared__ float msgT[64*132];
  __shared__ float alphaL[64];
  __shared__ int dstL[64];
  const int t = threadIdx.x;
  const int base = blockIdx.x * 64;
  if (t < 64){
    int e_ = base + t;
    int d = dst[e_];
    float den = denom[d];
    alphaL[t] = wbuf[e_] / ((den > 0.f) ? den : 1.f);
    dstL[t] = d;
  }
  stage_gather_bf16(shT, h_in, src, base, t);
  __syncthreads();

  const int lane = t & 63, wv = t >> 6, m15 = lane & 15, q = lane >> 4;
  const int arow = wv*16 + m15;
  f32x4 acc[8];
  #pragma unroll
  for (int nt = 0; nt < 8; nt++) acc[nt] = (f32x4){0.f, 0.f, 0.f, 0.f};
  short8 af[4];
  #pragma unroll
  for (int ks = 0; ks < 4; ks++)
    af[ks] = *(const short8*)(shT + arow*136 + ks*32 + q*8);
  gemm8(acc, af, wtV, m15, q);

  float al[4];
  #pragma unroll
  for (int reg = 0; reg < 4; reg++) al[reg] = alphaL[wv*16 + q*4 + reg];
  #pragma unroll
  for (int nt = 0; nt < 8; nt++){
    #pragma unroll
    for (int reg = 0; reg < 4; reg++)
      msgT[(wv*16 + q*4 + reg)*132 + nt*16 + m15] = al[reg]*acc[nt][reg];
  }
  __syncthreads();
  #pragma unroll 4
  for (int i = 0; i < 32; i++){
    int idx = i*256 + t;
    int r = idx >> 7, col = idx & 127;
    atomicAdd(agg + (size_t)dstL[r]*DD + col, msgT[r*132 + col]);
  }
}

__global__ void h_stats_k(const float* __restrict__ h_in, const float* __restrict__ agg,
                          float* __restrict__ hsum, float* __restrict__ hsum2){
  int col = threadIdx.x & 127, half = threadIdx.x >> 7;
  int r0 = blockIdx.x*64 + half*32;
  float s = 0.f, s2 = 0.f;
  for (int r = r0; r < r0 + 32; r++){
    if (r < NN){
      size_t o = (size_t)r*DD + col;
      float v = h_in[o] + agg[o];
      s += v; s2 += v*v;
    }
  }
  atomicAdd(hsum + col, s);
  atomicAdd(hsum2 + col, s2);
}

// S layout (floats): [hsum 0][hsum2 128][esum 256][esum2 384][sch 512][shh 640][sce 768][she 896]
__global__ void finalize_k(float* __restrict__ S,
                           const float* __restrict__ gh, const float* __restrict__ bh,
                           const float* __restrict__ ge, const float* __restrict__ be){
  int d = threadIdx.x & 127;
  bool is_e = threadIdx.x >= 128;
  const float* s1 = S + (is_e ? 256 : 0);
  const float* s2 = s1 + 128;
  float cnt = is_e ? (float)EE : (float)NN;
  float mu = s1[d] / cnt;
  float var = s2[d] / cnt - mu*mu;
  float rs = rsqrtf(var + 1e-5f);
  const float* g = is_e ? ge : gh;
  const float* b = is_e ? be : bh;
  float scale = rs * g[d];
  S[(is_e ? 768 : 512) + d] = scale;
  S[(is_e ? 896 : 640) + d] = b[d] - mu*scale;
}

__global__ void h_norm_k(const float* __restrict__ h_in, const float* __restrict__ agg,
                         const float* __restrict__ S, float* __restrict__ h_out){
  size_t i = ((size_t)blockIdx.x*256 + threadIdx.x)*4;
  int col = (int)(i & 127);
  float4 a = *(const float4*)(h_in + i);
  float4 g = *(const float4*)(agg + i);
  const float* sc = S + 512; const float* sh = S + 640;
  float4 v;
  v.x = fmaxf((a.x + g.x)*sc[col+0] + sh[col+0], 0.f);
  v.y = fmaxf((a.y + g.y)*sc[col+1] + sh[col+1], 0.f);
  v.z = fmaxf((a.z + g.z)*sc[col+2] + sh[col+2], 0.f);
  v.w = fmaxf((a.w + g.w)*sc[col+3] + sh[col+3], 0.f);
  *(float4*)(h_out + i) = v;
}

__global__ void e_norm_k(float* __restrict__ xe, const float* __restrict__ S){
  size_t i = ((size_t)blockIdx.x*256 + threadIdx.x)*4;
  int col = (int)(i & 127);
  float4 v = *(float4*)(xe + i);
  const float* sc = S + 768; const float* sh = S + 896;
  v.x = fmaxf(v.x*sc[col+0] + sh[col+0], 0.f);
  v.y = fmaxf(v.y*sc[col+1] + sh[col+1], 0.f);
  v.z = fmaxf(v.z*sc[col+2] + sh[col+2], 0.f);
  v.w = fmaxf(v.w*sc[col+3] + sh[col+3], 0.f);
  *(float4*)(xe + i) = v;
}

extern "C" void kernel_launch(void* const* d_in, const int* in_sizes, int n_in,
                              void* d_out, int out_size, void* d_ws, size_t ws_size,
                              hipStream_t stream){
  const float* h0  = (const float*)d_in[0];
  const float* e0  = (const float*)d_in[1];
  const int*  src  = (const int*)d_in[2];
  const int*  dst  = (const int*)d_in[3];
  const float* A   = (const float*)d_in[4];
  const float* B   = (const float*)d_in[5];
  const float* C   = (const float*)d_in[6];
  const float* V   = (const float*)d_in[7];
  const float* attn= (const float*)d_in[8];
  const float* gh  = (const float*)d_in[9];
  const float* bh  = (const float*)d_in[10];
  const float* ge  = (const float*)d_in[11];
  const float* be  = (const float*)d_in[12];

  // ws layout (~55.4 MB): WT | logits | ws_h | [zeroed: mmax | denom | S | agg]
  char* w = (char*)d_ws;
  unsigned short* WT = (unsigned short*)w;                 // 16*128*136*2 = 557056
  float* logits = (float*)(w + 557056);                    // E*4 = 3200000
  float* ws_h   = (float*)(w + 557056 + 3200000);          // N*128*4 = 25600000
  char*  zbase  = w + 557056 + 3200000 + 25600000;
  unsigned* mmax = (unsigned*)zbase;                       // N*4
  float* denom  = (float*)(zbase + 200000);                // N*4
  float* S      = (float*)(zbase + 400000);                // 1024 floats
  float* agg    = (float*)(zbase + 404096);                // N*128*4
  const size_t ZBYTES = 200000 + 200000 + 4096 + (size_t)NN*DD*4;

  float* hout_sec = (float*)d_out;                         // final h location
  float* ebuf = (float*)d_out + (size_t)NN*DD;             // e ping buffer == final e location

  prep_weights_k<<<1024, 256, 0, stream>>>(A, B, C, V, WT);

  const float* h_ins[4]  = { h0,   ws_h,     hout_sec, ws_h };
  float*       h_outs[4] = { ws_h, hout_sec, ws_h,     hout_sec };

  for (int l = 0; l < LL; l++){
    hipMemsetAsync(zbase, 0, ZBYTES, stream);
    const unsigned short* wtA = WT + (size_t)(l*4 + 0)*DD*136;
    const unsigned short* wtB = WT + (size_t)(l*4 + 1)*DD*136;
    const unsigned short* wtC = WT + (size_t)(l*4 + 2)*DD*136;
    const unsigned short* wtV = WT + (size_t)(l*4 + 3)*DD*136;
    const float* e_in = (l == 0) ? e0 : ebuf;

    edge_pre_k<<<EE/64, 256, 0, stream>>>(h_ins[l], e_in, src, dst,
        wtA, wtB, wtC, attn + l*DD, ebuf, logits, mmax, S + 256, S + 384);
    edge_w_k<<<EE/256, 256, 0, stream>>>(logits, dst, mmax, denom);
    edge_msg_k<<<EE/64, 256, 0, stream>>>(h_ins[l], src, dst, wtV, logits, denom, agg);
    h_stats_k<<<(NN + 63)/64, 256, 0, stream>>>(h_ins[l], agg, S, S + 128);
    finalize_k<<<1, 256, 0, stream>>>(S, gh + l*DD, bh + l*DD, ge + l*DD, be + l*DD);
    h_norm_k<<<(NN*DD)/1024, 256, 0, stream>>>(h_ins[l], agg, S, h_outs[l]);
    e_norm_k<<<(EE*DD)/1024, 256, 0, stream>>>(ebuf, S);
  }
}